// Round 5
// baseline (168.639 us; speedup 1.0000x reference)
//
#include <hip/hip_runtime.h>
#include <math.h>

// EKF propagate: B=65536 elements, nx=16, nz=8, nu=4, fp32.
// 16 lanes per element (lane t owns row t), 4 elements/wave, 16/block.
// No __syncthreads: cross-lane traffic is intra-wave (per-group LDS slices
// + __shfl); __builtin_amdgcn_wave_barrier pins compiler ordering only.
//
// R5 change vs R4 (66.6us, VALUBusy 61%, Occ 42%): latency-bound at 6
// blocks/CU. Shrink LDS 27136->18944 B (GS 424->296) so 8 blocks/CU fit
// (32-wave ceiling, and 16 blocks/CU drain in exactly 2 rounds):
//  - mubar/d/h/dh vectors move from LDS to __shfl gathers (lane m owns
//    row m; sources always active at the gather sites).
//  - h computed on all 16 lanes (row t&7) -- same instr count as the
//    old masked version, full lane utilization, enables shfl of h/dh.
//  - VT/TPT stride 20->18 (float2 reads; scatter banks 18t%32 distinct).
// VGPR must stay <=64 for 8 waves/SIMD (R4: 48). NO min-waves clause in
// __launch_bounds__ (R3: it forced 68->40 VGPR via scratch spills).

namespace {

constexpr int GROUPS = 16;            // elements per block
constexpr int TPB    = GROUPS * 16;   // 256 threads

// Per-group LDS layout (floats), overlaid by liveness:
//  [0,288): VT (16x18) until the W-phase read; then TPT (8x18) + TPB;
//           then SI/PIV overlay the dead TPT.
constexpr int O_VT  = 0;    // 16 rows x 18 (V^T)        [V-scatter .. W-read]
constexpr int O_TPT = 0;    // 8 rows x 18 (tp^T)        [tp .. S-build]
constexpr int O_SI  = 0;    // 8 x 8 S^-1 rows           [GJ-end .. K-build]
constexpr int O_PIV = 64;   // 16 pivot scratch          [GJ only]
constexpr int O_TPB = 144;  // 16 x 8 tp rows            [tp .. final]
constexpr int GS    = 296;  // 18944 B/block -> 8 blocks/CU; GS%32==8 ->
                            // the 4 groups of a wave sit at bank offsets
                            // {0,8,16,24}: group-broadcasts conflict-free

__device__ __forceinline__ float dot4(float4 a, float4 b) {
  return a.x*b.x + a.y*b.y + a.z*b.z + a.w*b.w;
}

__global__ __launch_bounds__(TPB)
void ekf_kernel(const float* __restrict__ mu_prev,
                const float* __restrict__ Sig_prev,
                const float* __restrict__ U,
                const float* __restrict__ Z,
                const float* __restrict__ A,
                const float* __restrict__ Bm,
                const float* __restrict__ C,
                const float* __restrict__ Q,
                const float* __restrict__ R,
                float* __restrict__ mu_out,
                float* __restrict__ sig_out,
                int Btot)
{
  __shared__ float lds[GS * GROUPS];   // 18944 B
  const int tid = threadIdx.x;
  const int g = tid >> 4;
  const int t = tid & 15;
  int e = blockIdx.x * GROUPS + g;
  if (e >= Btot) e = Btot - 1;         // clamp; duplicate-write benign
  float* L = lds + g * GS;

  // ---- load Sigma row t (coalesced: wave covers a contiguous 4KB) ----
  float sig[16];
  {
    const float4* sp = (const float4*)(Sig_prev + (size_t)e * 256 + t * 16);
    #pragma unroll
    for (int c = 0; c < 4; c++) {
      float4 v = sp[c];
      sig[4*c+0] = v.x; sig[4*c+1] = v.y; sig[4*c+2] = v.z; sig[4*c+3] = v.w;
    }
  }

  // ---- mu_bar_t = tanh(A[t,:].mu + Bm[t,:].u), d_t = 1 - mu_bar^2 ----
  float pre;
  {
    const float4* ar = (const float4*)(A + t * 16);      // L1 row read
    const float4* mr = (const float4*)(mu_prev + (size_t)e * 16);
    pre = dot4(ar[0], mr[0]) + dot4(ar[1], mr[1])
        + dot4(ar[2], mr[2]) + dot4(ar[3], mr[3]);
    float4 b4 = *(const float4*)(Bm + t * 4);
    float4 u4 = *(const float4*)(U + (size_t)e * 4);
    pre += dot4(b4, u4);
  }
  const float mubar = tanhf(pre);
  const float dloc  = 1.0f - mubar * mubar;

  // ---- h row (t&7) on ALL lanes: ph = C[r,:].mubar via shfl gather ----
  float hloc, dhloc;
  {
    const int r = t & 7;
    const float4* cr = (const float4*)(C + r * 16);      // per-lane L1 read
    float4 c0 = cr[0], c1 = cr[1], c2 = cr[2], c3 = cr[3];
    float ph;
    ph  = c0.x*__shfl(mubar, 0,16) + c0.y*__shfl(mubar, 1,16)
        + c0.z*__shfl(mubar, 2,16) + c0.w*__shfl(mubar, 3,16);
    ph += c1.x*__shfl(mubar, 4,16) + c1.y*__shfl(mubar, 5,16)
        + c1.z*__shfl(mubar, 6,16) + c1.w*__shfl(mubar, 7,16);
    ph += c2.x*__shfl(mubar, 8,16) + c2.y*__shfl(mubar, 9,16)
        + c2.z*__shfl(mubar,10,16) + c2.w*__shfl(mubar,11,16);
    ph += c3.x*__shfl(mubar,12,16) + c3.y*__shfl(mubar,13,16)
        + c3.z*__shfl(mubar,14,16) + c3.w*__shfl(mubar,15,16);
    hloc  = tanhf(ph);
    dhloc = 1.0f - hloc * hloc;
  }

  // ---- V = Sig * A^T (row t local; A rows via s_load), scatter V^T ----
  #pragma unroll
  for (int j = 0; j < 16; j++) {
    float acc = 0.f;
    #pragma unroll
    for (int k = 0; k < 16; k++) acc += sig[k] * A[j*16 + k];  // uniform -> s_load
    L[O_VT + j*18 + t] = acc;       // banks (18t)%32 all-distinct
  }
  __builtin_amdgcn_wave_barrier();

  // ---- W col t = A * V[:,t]  (== W row t, W symmetric) ----
  float sb[16];
  {
    float vcol[16];
    const float2* vt = (const float2*)(L + O_VT + t*18);
    #pragma unroll
    for (int c = 0; c < 8; c++) {
      float2 v = vt[c];
      vcol[2*c+0] = v.x; vcol[2*c+1] = v.y;
    }
    #pragma unroll
    for (int i = 0; i < 16; i++) {
      float acc = 0.f;
      #pragma unroll
      for (int k = 0; k < 16; k++) acc += A[i*16 + k] * vcol[k]; // s_load
      sb[i] = acc;
    }
  }
  __builtin_amdgcn_wave_barrier();   // VT dead; TPT/TPB/SI/PIV may overlay

  // ---- Sig_bar row t = R[t,:] + d_t * W[t,:] .* d  (d via shfl) ----
  {
    const float4* rr = (const float4*)(R + t * 16);
    float4 r0 = rr[0], r1 = rr[1], r2 = rr[2], r3 = rr[3];
    sb[ 0] = r0.x + dloc * sb[ 0] * __shfl(dloc, 0,16);
    sb[ 1] = r0.y + dloc * sb[ 1] * __shfl(dloc, 1,16);
    sb[ 2] = r0.z + dloc * sb[ 2] * __shfl(dloc, 2,16);
    sb[ 3] = r0.w + dloc * sb[ 3] * __shfl(dloc, 3,16);
    sb[ 4] = r1.x + dloc * sb[ 4] * __shfl(dloc, 4,16);
    sb[ 5] = r1.y + dloc * sb[ 5] * __shfl(dloc, 5,16);
    sb[ 6] = r1.z + dloc * sb[ 6] * __shfl(dloc, 6,16);
    sb[ 7] = r1.w + dloc * sb[ 7] * __shfl(dloc, 7,16);
    sb[ 8] = r2.x + dloc * sb[ 8] * __shfl(dloc, 8,16);
    sb[ 9] = r2.y + dloc * sb[ 9] * __shfl(dloc, 9,16);
    sb[10] = r2.z + dloc * sb[10] * __shfl(dloc,10,16);
    sb[11] = r2.w + dloc * sb[11] * __shfl(dloc,11,16);
    sb[12] = r3.x + dloc * sb[12] * __shfl(dloc,12,16);
    sb[13] = r3.y + dloc * sb[13] * __shfl(dloc,13,16);
    sb[14] = r3.z + dloc * sb[14] * __shfl(dloc,14,16);
    sb[15] = r3.w + dloc * sb[15] * __shfl(dloc,15,16);
  }

  // ---- tp row t = Sig_bar[t,:] C^T Dh ; stash transposed + row-major ----
  float tp[8];
  #pragma unroll
  for (int m = 0; m < 8; m++) {
    float acc = 0.f;
    #pragma unroll
    for (int k = 0; k < 16; k++) acc += sb[k] * C[m*16 + k];    // s_load
    tp[m] = acc * __shfl(dhloc, m, 16);   // dh_m owned by lane m
    L[O_TPT + m*18 + t] = tp[m];
  }
  *((float4*)(L + O_TPB + t*8 + 0)) = make_float4(tp[0], tp[1], tp[2], tp[3]);
  *((float4*)(L + O_TPB + t*8 + 4)) = make_float4(tp[4], tp[5], tp[6], tp[7]);
  __builtin_amdgcn_wave_barrier();

  // ---- S col t (== row t, S symmetric), Gauss-Jordan inverse (t<8) ----
  if (t < 8) {
    float tcol[16];
    const float2* tt = (const float2*)(L + O_TPT + t*18);
    #pragma unroll
    for (int c = 0; c < 8; c++) {
      float2 v = tt[c];
      tcol[2*c+0] = v.x; tcol[2*c+1] = v.y;
    }
    float s8[8];
    {
      float4 q0 = *(const float4*)(Q + t*8);       // Q row t == col t (sym)
      float4 q1 = *(const float4*)(Q + t*8 + 4);
      float qv[8] = {q0.x,q0.y,q0.z,q0.w,q1.x,q1.y,q1.z,q1.w};
      #pragma unroll
      for (int m = 0; m < 8; m++) {
        float acc = 0.f;
        #pragma unroll
        for (int k = 0; k < 16; k++) acc += C[m*16 + k] * tcol[k]; // s_load
        s8[m] = acc * __shfl(dhloc, m, 16) + qv[m];  // src lanes m<8 active
      }
    }

    // Gauss-Jordan (S is SPD -> no pivoting); rows live in registers.
    float x8[8];
    #pragma unroll
    for (int j = 0; j < 8; j++) x8[j] = (j == t) ? 1.0f : 0.0f;
    #pragma unroll
    for (int p = 0; p < 8; p++) {
      if (t == p) {
        float rcp = 1.0f / s8[p];   // IEEE div (no fast-math)
        #pragma unroll
        for (int j = 0; j < 8; j++) { s8[j] *= rcp; x8[j] *= rcp; }
        *((float4*)(L + O_PIV + 0))  = make_float4(s8[0], s8[1], s8[2], s8[3]);
        *((float4*)(L + O_PIV + 4))  = make_float4(s8[4], s8[5], s8[6], s8[7]);
        *((float4*)(L + O_PIV + 8))  = make_float4(x8[0], x8[1], x8[2], x8[3]);
        *((float4*)(L + O_PIV + 12)) = make_float4(x8[4], x8[5], x8[6], x8[7]);
      }
      __builtin_amdgcn_wave_barrier();
      if (t != p) {
        float f = s8[p];
        float4 pa = *(const float4*)(L + O_PIV + 0);
        float4 pb = *(const float4*)(L + O_PIV + 4);
        float4 pc = *(const float4*)(L + O_PIV + 8);
        float4 pd = *(const float4*)(L + O_PIV + 12);
        s8[0]-=f*pa.x; s8[1]-=f*pa.y; s8[2]-=f*pa.z; s8[3]-=f*pa.w;
        s8[4]-=f*pb.x; s8[5]-=f*pb.y; s8[6]-=f*pb.z; s8[7]-=f*pb.w;
        x8[0]-=f*pc.x; x8[1]-=f*pc.y; x8[2]-=f*pc.z; x8[3]-=f*pc.w;
        x8[4]-=f*pd.x; x8[5]-=f*pd.y; x8[6]-=f*pd.z; x8[7]-=f*pd.w;
      }
      __builtin_amdgcn_wave_barrier();
    }
    *((float4*)(L + O_SI + t*8 + 0)) = make_float4(x8[0], x8[1], x8[2], x8[3]);
    *((float4*)(L + O_SI + t*8 + 4)) = make_float4(x8[4], x8[5], x8[6], x8[7]);
  }
  __builtin_amdgcn_wave_barrier();

  // ---- K row t = tp[t,:] @ Sinv ----
  float kreg[8] = {0,0,0,0,0,0,0,0};
  #pragma unroll
  for (int m = 0; m < 8; m++) {
    float tpm = tp[m];
    float4 a = *(const float4*)(L + O_SI + m*8 + 0);
    float4 b = *(const float4*)(L + O_SI + m*8 + 4);
    kreg[0]+=tpm*a.x; kreg[1]+=tpm*a.y; kreg[2]+=tpm*a.z; kreg[3]+=tpm*a.w;
    kreg[4]+=tpm*b.x; kreg[5]+=tpm*b.y; kreg[6]+=tpm*b.z; kreg[7]+=tpm*b.w;
  }

  // ---- mu_now_t = mu_bar_t + K[t,:].(z - h_bar)  (h via shfl) ----
  {
    float4 z0 = *(const float4*)(Z + (size_t)e * 8);
    float4 z1 = *(const float4*)(Z + (size_t)e * 8 + 4);
    float mu_now = mubar
      + kreg[0]*(z0.x-__shfl(hloc,0,16)) + kreg[1]*(z0.y-__shfl(hloc,1,16))
      + kreg[2]*(z0.z-__shfl(hloc,2,16)) + kreg[3]*(z0.w-__shfl(hloc,3,16))
      + kreg[4]*(z1.x-__shfl(hloc,4,16)) + kreg[5]*(z1.y-__shfl(hloc,5,16))
      + kreg[6]*(z1.z-__shfl(hloc,6,16)) + kreg[7]*(z1.w-__shfl(hloc,7,16));
    mu_out[(size_t)e * 16 + t] = mu_now;
  }

  // ---- Sig_now = Sig_bar - K tp^T  (== Joseph exactly: K S = tp) ----
  float out[16];
  #pragma unroll
  for (int i = 0; i < 16; i++) {
    float4 ta = *(const float4*)(L + O_TPB + i*8 + 0);
    float4 tb = *(const float4*)(L + O_TPB + i*8 + 4);
    float acc = sb[i];
    acc -= kreg[0]*ta.x + kreg[1]*ta.y + kreg[2]*ta.z + kreg[3]*ta.w
         + kreg[4]*tb.x + kreg[5]*tb.y + kreg[6]*tb.z + kreg[7]*tb.w;
    out[i] = acc;
  }
  {
    float4* op = (float4*)(sig_out + (size_t)e * 256 + t * 16);
    op[0] = make_float4(out[0],  out[1],  out[2],  out[3]);
    op[1] = make_float4(out[4],  out[5],  out[6],  out[7]);
    op[2] = make_float4(out[8],  out[9],  out[10], out[11]);
    op[3] = make_float4(out[12], out[13], out[14], out[15]);
  }
}

} // namespace

extern "C" void kernel_launch(void* const* d_in, const int* in_sizes, int n_in,
                              void* d_out, int out_size, void* d_ws, size_t ws_size,
                              hipStream_t stream)
{
  const float* mu_prev = (const float*)d_in[0];
  const float* Sigma   = (const float*)d_in[1];
  const float* u       = (const float*)d_in[2];
  const float* z       = (const float*)d_in[3];
  const float* A       = (const float*)d_in[4];
  const float* Bm      = (const float*)d_in[5];
  const float* C       = (const float*)d_in[6];
  const float* Q       = (const float*)d_in[7];
  const float* R       = (const float*)d_in[8];

  const int Btot = in_sizes[0] / 16;                 // B = 65536
  float* mu_out  = (float*)d_out;
  float* sig_out = (float*)d_out + (size_t)Btot * 16;

  const int grid = (Btot + GROUPS - 1) / GROUPS;     // 4096 blocks x 256 thr
  ekf_kernel<<<grid, TPB, 0, stream>>>(mu_prev, Sigma, u, z, A, Bm, C, Q, R,
                                       mu_out, sig_out, Btot);
}